// Round 4
// baseline (157.470 us; speedup 1.0000x reference)
//
#include <hip/hip_runtime.h>
#include <hip/hip_bf16.h>

#define N_PTS 65536
#define LOG2E 1.4426950408889634f

typedef __attribute__((ext_vector_type(8))) short short8;
typedef __attribute__((ext_vector_type(4))) float float4v;

#if __has_builtin(__builtin_amdgcn_exp2f)
#define EXP2F(x) __builtin_amdgcn_exp2f(x)
#else
#define EXP2F(x) exp2f(x)
#endif

__device__ __forceinline__ short f2b(float f) {
    __hip_bfloat16 h = __float2bfloat16(f);
    return *(short*)&h;
}
__device__ __forceinline__ float b2f(short s) {
    __hip_bfloat16 h = *(__hip_bfloat16*)&s;
    return __bfloat162float(h);
}

// ---------------- prep (identical layout to R3) ----------------
//   zb   [1024][16] bf16  @ 0        bf16(log2e * z)
//   FbB  [8][64][16] bf16 @ 32768    FbB[o][l][i] = bf16(F[o][i][l])
//   BWd  [64][512] bf16   @ 49152    block-diag sqrt(2/64)*pw
//   Wtb  [64][1024] bf16  @ 114688   bf16(W)
//   z2h  [1024] f32       @ 245760   0.5*log2e*||bf16(z_m)||^2
__global__ __launch_bounds__(256) void prep_kernel(
    const float* __restrict__ z, const float* __restrict__ W,
    const float* __restrict__ F, const float* __restrict__ pw,
    short* __restrict__ zb, short* __restrict__ FbB,
    short* __restrict__ BWd, short* __restrict__ Wtb,
    float* __restrict__ z2h)
{
    int t = blockIdx.x * 256 + threadIdx.x;
    if (t < 16384) {
        zb[t] = f2b(LOG2E * z[t]);
    } else if (t < 17408) {
        int m = t - 16384;
        const float4v* zp = (const float4v*)(z + (size_t)m * 16);
        float s = 0.f;
        #pragma unroll
        for (int k = 0; k < 4; k++) {
            float4v v = zp[k];
            float a0 = b2f(f2b(v.x)), a1 = b2f(f2b(v.y));
            float a2 = b2f(f2b(v.z)), a3 = b2f(f2b(v.w));
            s += a0 * a0 + a1 * a1 + a2 * a2 + a3 * a3;
        }
        z2h[m] = 0.5f * LOG2E * s;
    } else if (t < 25600) {
        int p = t - 17408;
        int o = p >> 10, l = (p >> 4) & 63, i = p & 15;
        FbB[p] = f2b(F[o * 1024 + i * 64 + l]);
    } else if (t < 58368) {
        int p = t - 25600;
        int so = p >> 9, ol = p & 511, o = ol >> 6;
        float v = ((so & 7) == o) ? 0.17677669529663687f * pw[so * 64 + (ol & 63)] : 0.f;
        BWd[p] = f2b(v);
    } else if (t < 123904) {
        int p = t - 58368;
        Wtb[p] = f2b(W[p]);
    }
}

// ---------------- fused prior + data ----------------
// 512 thr (8 waves), n-block 64, tile 64x128 bf16, XOR-swizzled, double-
// buffered, one barrier per chunk. LDS 33 KB -> 4 blocks/CU = 32 waves/CU.
// Wave w: s = w&3 (so-strip + production row-strip), h = w>>2 (production
// column half / GEMM n-half).
// Swizzle: element (row, col) lives at block (col>>3) ^ (row&7), offset col&7
// (16-B blocks; row stride 128 shorts). GEMM b128 reads: 8 dwords/bank/instr
// = LDS hardware minimum (conflict-free).
__global__ __launch_bounds__(512, 8) void fused_kernel(
    const float* __restrict__ x, const float* __restrict__ ph,
    const short* __restrict__ zb, const short* __restrict__ FbB,
    const short* __restrict__ BWd, const short* __restrict__ Wtb,
    const float* __restrict__ z2h, float* __restrict__ out)
{
    __shared__ __align__(16) short tile[2][64 * 128];
    __shared__ float x2c[64];

    const int tid = threadIdx.x;
    const int lane = tid & 63, w = tid >> 6;
    const int q = lane >> 4, c = lane & 15;
    const int s = w & 3, h = w >> 2;
    const int n0 = blockIdx.x * 64;

    if (tid < 64) {
        float sum = 0.f;
        const float4v* xr = (const float4v*)(x + (size_t)(n0 + tid) * 16);
        #pragma unroll
        for (int k = 0; k < 4; k++) {
            float4v v = xr[k];
            float a0 = b2f(f2b(v.x)), a1 = b2f(f2b(v.y));
            float a2 = b2f(f2b(v.z)), a3 = b2f(f2b(v.w));
            sum += a0 * a0 + a1 * a1 + a2 * a2 + a3 * a3;
        }
        x2c[tid] = 0.5f * LOG2E * sum;
    }

    // x A-fragment for row-strip s (K=16 real, quads 2,3 zero)
    short8 ax = (short8)0;
    if (q < 2) {
        const float4v* xp = (const float4v*)(x + (size_t)(n0 + 16 * s + c) * 16 + q * 8);
        float4v v0 = xp[0], v1 = xp[1];
        ax[0] = f2b(v0.x); ax[1] = f2b(v0.y); ax[2] = f2b(v0.z); ax[3] = f2b(v0.w);
        ax[4] = f2b(v1.x); ax[5] = f2b(v1.y); ax[6] = f2b(v1.z); ax[7] = f2b(v1.w);
    }

    float4v acc[2];
    acc[0] = (float4v)(0.f);
    acc[1] = (float4v)(0.f);

    __syncthreads();

    // ============ prior: cos(x.F + ph) @ blockdiag(pws), 4 chunks of 128 ============
    #pragma unroll
    for (int p = 0; p < 4; p++) {
        short* tl = tile[p & 1];
        const int colbase = p * 128 + 64 * h;
        #pragma unroll
        for (int lt = 0; lt < 4; lt++) {
            const int f = colbase + lt * 16 + c;          // global feature idx 0..511
            short8 bf = (short8)0;
            if (q < 2) bf = *(const short8*)(FbB + (f * 16 + q * 8));
            float phv = ph[f];
            float4v c0 = {phv, phv, phv, phv};
            float4v d = __builtin_amdgcn_mfma_f32_16x16x32_bf16(ax, bf, c0, 0, 0, 0);
            const int wb = 8 * h + 2 * lt + (c >> 3);
            #pragma unroll
            for (int r = 0; r < 4; r++) {
                const int row = 16 * s + 4 * q + r;
                tl[row * 128 + ((wb ^ (row & 7)) * 8) + (c & 7)] = f2b(__cosf(d[r]));
            }
        }
        short8 aw[4];
        #pragma unroll
        for (int ks = 0; ks < 4; ks++)
            aw[ks] = *(const short8*)(BWd + ((16 * s + c) * 512 + p * 128 + ks * 32 + q * 8));
        __syncthreads();
        #pragma unroll
        for (int ks = 0; ks < 4; ks++) {
            #pragma unroll
            for (int ntl = 0; ntl < 2; ntl++) {
                const int row = (2 * h + ntl) * 16 + c;
                short8 bb = *(const short8*)(tl + row * 128 + (((ks * 4 + q) ^ (c & 7)) * 8));
                acc[ntl] = __builtin_amdgcn_mfma_f32_16x16x32_bf16(aw[ks], bb, acc[ntl], 0, 0, 0);
            }
        }
    }

    float mx2[4];
    #pragma unroll
    for (int r = 0; r < 4; r++) mx2[r] = -x2c[16 * s + 4 * q + r];

    // ============ data: exp2(dot*log2e - (x2+z2)*log2e/2) @ W^T, 8 chunks ============
    #pragma unroll
    for (int mc = 0; mc < 8; mc++) {
        short* tl = tile[mc & 1];
        const int colbase = mc * 128 + 64 * h;
        #pragma unroll
        for (int mt = 0; mt < 4; mt++) {
            const int m = colbase + mt * 16 + c;          // global m idx 0..1023
            short8 bz = (short8)0;
            if (q < 2) bz = *(const short8*)(zb + (m * 16 + q * 8));
            float z2v = z2h[m];
            float4v c0;
            #pragma unroll
            for (int r = 0; r < 4; r++) c0[r] = mx2[r] - z2v;
            float4v d = __builtin_amdgcn_mfma_f32_16x16x32_bf16(ax, bz, c0, 0, 0, 0);
            const int wb = 8 * h + 2 * mt + (c >> 3);
            #pragma unroll
            for (int r = 0; r < 4; r++) {
                const int row = 16 * s + 4 * q + r;
                tl[row * 128 + ((wb ^ (row & 7)) * 8) + (c & 7)] = f2b(EXP2F(d[r]));
            }
        }
        short8 aw[4];
        #pragma unroll
        for (int ks = 0; ks < 4; ks++)
            aw[ks] = *(const short8*)(Wtb + ((16 * s + c) * 1024 + mc * 128 + ks * 32 + q * 8));
        __syncthreads();
        #pragma unroll
        for (int ks = 0; ks < 4; ks++) {
            #pragma unroll
            for (int ntl = 0; ntl < 2; ntl++) {
                const int row = (2 * h + ntl) * 16 + c;
                short8 bb = *(const short8*)(tl + row * 128 + (((ks * 4 + q) ^ (c & 7)) * 8));
                acc[ntl] = __builtin_amdgcn_mfma_f32_16x16x32_bf16(aw[ks], bb, acc[ntl], 0, 0, 0);
            }
        }
    }

    // epilogue: D[row=q*4+r -> so=16s+..][col=c -> n], n-tiles 2h, 2h+1
    #pragma unroll
    for (int ntl = 0; ntl < 2; ntl++) {
        #pragma unroll
        for (int r = 0; r < 4; r++) {
            out[(size_t)(16 * s + 4 * q + r) * N_PTS + n0 + (2 * h + ntl) * 16 + c] = acc[ntl][r];
        }
    }
}

extern "C" void kernel_launch(void* const* d_in, const int* in_sizes, int n_in,
                              void* d_out, int out_size, void* d_ws, size_t ws_size,
                              hipStream_t stream) {
    const float* x  = (const float*)d_in[0];   // [65536][16]
    const float* z  = (const float*)d_in[1];   // [1024][16]
    const float* W  = (const float*)d_in[2];   // [8][8][1024] = [64][1024]
    const float* F  = (const float*)d_in[3];   // [8][16][64]
    const float* ph = (const float*)d_in[4];   // [8][64]
    const float* pw = (const float*)d_in[5];   // [8][8][64] = [64][64]
    float* out = (float*)d_out;                // [64][65536]

    char* ws = (char*)d_ws;
    short* zb  = (short*)(ws);            // 32768 B
    short* FbB = (short*)(ws + 32768);    // 16384 B
    short* BWd = (short*)(ws + 49152);    // 65536 B
    short* Wtb = (short*)(ws + 114688);   // 131072 B
    float* z2h = (float*)(ws + 245760);   // 4096 B

    prep_kernel<<<484, 256, 0, stream>>>(z, W, F, pw, zb, FbB, BWd, Wtb, z2h);
    fused_kernel<<<1024, 512, 0, stream>>>(x, ph, zb, FbB, BWd, Wtb, z2h, out);
}

// Round 5
// 135.999 us; speedup vs baseline: 1.1579x; 1.1579x over previous
//
#include <hip/hip_runtime.h>
#include <hip/hip_bf16.h>

#define N_PTS 65536
#define LOG2E 1.4426950408889634f
#define INV2PI 0.15915494309189535f

typedef __attribute__((ext_vector_type(8))) short short8;
typedef __attribute__((ext_vector_type(4))) short short4v;
typedef __attribute__((ext_vector_type(4))) float float4v;

#if __has_builtin(__builtin_amdgcn_exp2f)
#define EXP2F(x) __builtin_amdgcn_exp2f(x)
#else
#define EXP2F(x) exp2f(x)
#endif

// cos with argument in revolutions (weights pre-scaled by 1/2pi in prep):
// v_fract -> [0,1), then v_cos (HW cos takes revolutions per gfx950 ISA).
#if __has_builtin(__builtin_amdgcn_cosf) && __has_builtin(__builtin_amdgcn_fractf)
#define COS_REV(v) __builtin_amdgcn_cosf(__builtin_amdgcn_fractf(v))
#else
#define COS_REV(v) __cosf((v) * 6.283185307179586f)
#endif

__device__ __forceinline__ short f2b(float f) {
    __hip_bfloat16 h = __float2bfloat16(f);
    return *(short*)&h;
}
__device__ __forceinline__ float b2f(short s) {
    __hip_bfloat16 h = *(__hip_bfloat16*)&s;
    return __bfloat162float(h);
}

// ---------------- prep ----------------
// ws layout (bytes):
//   zb   [1024][16] bf16 @ 0        bf16(log2e * z)
//   FbB  [512][16] bf16  @ 32768    FbB[o*64+l][i] = bf16(F[o][i][l] / 2pi)
//   BWd  [64][512] bf16  @ 49152    block-diag sqrt(2/64)*pw
//   Wtb  [64][1024] bf16 @ 114688   bf16(W)
//   z2h  [1024] f32      @ 245760   0.5*log2e*||bf16(z_m)||^2
//   phs  [512] f32       @ 249856   ph / 2pi
__global__ __launch_bounds__(256) void prep_kernel(
    const float* __restrict__ z, const float* __restrict__ W,
    const float* __restrict__ F, const float* __restrict__ pw,
    const float* __restrict__ ph,
    short* __restrict__ zb, short* __restrict__ FbB,
    short* __restrict__ BWd, short* __restrict__ Wtb,
    float* __restrict__ z2h, float* __restrict__ phs)
{
    int t = blockIdx.x * 256 + threadIdx.x;
    if (t < 16384) {
        zb[t] = f2b(LOG2E * z[t]);
    } else if (t < 17408) {
        int m = t - 16384;
        const float4v* zp = (const float4v*)(z + (size_t)m * 16);
        float s = 0.f;
        #pragma unroll
        for (int k = 0; k < 4; k++) {
            float4v v = zp[k];
            float a0 = b2f(f2b(v.x)), a1 = b2f(f2b(v.y));
            float a2 = b2f(f2b(v.z)), a3 = b2f(f2b(v.w));
            s += a0 * a0 + a1 * a1 + a2 * a2 + a3 * a3;
        }
        z2h[m] = 0.5f * LOG2E * s;
    } else if (t < 25600) {
        int p = t - 17408;
        int o = p >> 10, l = (p >> 4) & 63, i = p & 15;
        FbB[p] = f2b(INV2PI * F[o * 1024 + i * 64 + l]);
    } else if (t < 58368) {
        int p = t - 25600;
        int so = p >> 9, ol = p & 511, o = ol >> 6;
        float v = ((so & 7) == o) ? 0.17677669529663687f * pw[so * 64 + (ol & 63)] : 0.f;
        BWd[p] = f2b(v);
    } else if (t < 123904) {
        int p = t - 58368;
        Wtb[p] = f2b(W[p]);
    } else if (t < 124416) {
        int p = t - 123904;
        phs[p] = INV2PI * ph[p];
    }
}

// ---------------- fused prior + data ----------------
// 256 thr (4 waves), n-block 64. 128-wide chunks, double-buffered tile, one
// barrier per chunk. Tile row stride 132 shorts = 66 dwords == 2 (mod 32):
// GEMM b64 reads <=2-way bank-aliased (free), production b16 writes pair into
// single dwords (free). Production inputs for chunk k+1 prefetched into regs
// before the barrier of chunk k (L2 latency hidden behind GEMM phase).
__global__ __launch_bounds__(256, 4) void fused_kernel(
    const float* __restrict__ x,
    const short* __restrict__ zb, const short* __restrict__ FbB,
    const short* __restrict__ BWd, const short* __restrict__ Wtb,
    const float* __restrict__ z2h, const float* __restrict__ phs,
    float* __restrict__ out)
{
    __shared__ __align__(16) short tile[2][64 * 132];
    __shared__ float x2c[64];

    const int tid = threadIdx.x;
    const int lane = tid & 63, w = tid >> 6;
    const int q = lane >> 4, c = lane & 15;
    const int n0 = blockIdx.x * 64;

    if (tid < 64) {
        float s = 0.f;
        const float4v* xr = (const float4v*)(x + (size_t)(n0 + tid) * 16);
        #pragma unroll
        for (int k = 0; k < 4; k++) {
            float4v v = xr[k];
            float a0 = b2f(f2b(v.x)), a1 = b2f(f2b(v.y));
            float a2 = b2f(f2b(v.z)), a3 = b2f(f2b(v.w));
            s += a0 * a0 + a1 * a1 + a2 * a2 + a3 * a3;
        }
        x2c[tid] = 0.5f * LOG2E * s;
    }

    // x A-fragment (K=16 real, quads 2,3 zero)
    short8 ax = (short8)0;
    if (q < 2) {
        const float4v* xp = (const float4v*)(x + (size_t)(n0 + 16 * w + c) * 16 + q * 8);
        float4v v0 = xp[0], v1 = xp[1];
        ax[0] = f2b(v0.x); ax[1] = f2b(v0.y); ax[2] = f2b(v0.z); ax[3] = f2b(v0.w);
        ax[4] = f2b(v1.x); ax[5] = f2b(v1.y); ax[6] = f2b(v1.z); ax[7] = f2b(v1.w);
    }

    float4v acc[4];
    #pragma unroll
    for (int i = 0; i < 4; i++) acc[i] = (float4v)(0.f);

    __syncthreads();

    float mx2[4];
    #pragma unroll
    for (int r = 0; r < 4; r++) mx2[r] = -x2c[16 * w + 4 * q + r];

    // production-input prefetch registers
    short8 pb[8];
    float  psc[8];
    #pragma unroll
    for (int lt = 0; lt < 8; lt++) {                  // prior chunk 0
        int f = lt * 16 + c;
        pb[lt] = (q < 2) ? *(const short8*)(FbB + (f * 16 + q * 8)) : (short8)0;
        psc[lt] = phs[f];
    }

    // ============ prior: cos((x.F + ph)/2pi rev) @ blockdiag(pws), 4 chunks ============
    #pragma unroll
    for (int p = 0; p < 4; p++) {
        short* buf = tile[p & 1];
        #pragma unroll
        for (int lt = 0; lt < 8; lt++) {
            float4v c0 = {psc[lt], psc[lt], psc[lt], psc[lt]};
            float4v d = __builtin_amdgcn_mfma_f32_16x16x32_bf16(ax, pb[lt], c0, 0, 0, 0);
            #pragma unroll
            for (int r = 0; r < 4; r++)
                buf[(16 * w + 4 * q + r) * 132 + lt * 16 + c] = f2b(COS_REV(d[r]));
        }
        short8 aw[4];
        #pragma unroll
        for (int ks = 0; ks < 4; ks++)
            aw[ks] = *(const short8*)(BWd + ((16 * w + c) * 512 + p * 128 + ks * 32 + q * 8));
        if (p < 3) {
            #pragma unroll
            for (int lt = 0; lt < 8; lt++) {
                int f = (p + 1) * 128 + lt * 16 + c;
                pb[lt] = (q < 2) ? *(const short8*)(FbB + (f * 16 + q * 8)) : (short8)0;
                psc[lt] = phs[f];
            }
        } else {
            #pragma unroll
            for (int lt = 0; lt < 8; lt++) {          // data chunk 0
                int m = lt * 16 + c;
                pb[lt] = (q < 2) ? *(const short8*)(zb + (m * 16 + q * 8)) : (short8)0;
                psc[lt] = z2h[m];
            }
        }
        __syncthreads();
        #pragma unroll
        for (int ks = 0; ks < 4; ks++) {
            #pragma unroll
            for (int nt = 0; nt < 4; nt++) {
                const short* tp = buf + (nt * 16 + c) * 132 + ks * 32 + q * 8;
                short4v lo = *(const short4v*)tp;
                short4v hi = *(const short4v*)(tp + 4);
                short8 bb = __builtin_shufflevector(lo, hi, 0, 1, 2, 3, 4, 5, 6, 7);
                acc[nt] = __builtin_amdgcn_mfma_f32_16x16x32_bf16(aw[ks], bb, acc[nt], 0, 0, 0);
            }
        }
    }

    // ============ data: exp2(log2e*(dot - (x2+z2)/2)) @ W^T, 8 chunks ============
    #pragma unroll
    for (int mc = 0; mc < 8; mc++) {
        short* buf = tile[mc & 1];
        #pragma unroll
        for (int mt = 0; mt < 8; mt++) {
            float4v c0;
            #pragma unroll
            for (int r = 0; r < 4; r++) c0[r] = mx2[r] - psc[mt];
            float4v d = __builtin_amdgcn_mfma_f32_16x16x32_bf16(ax, pb[mt], c0, 0, 0, 0);
            #pragma unroll
            for (int r = 0; r < 4; r++)
                buf[(16 * w + 4 * q + r) * 132 + mt * 16 + c] = f2b(EXP2F(d[r]));
        }
        short8 aw[4];
        #pragma unroll
        for (int ks = 0; ks < 4; ks++)
            aw[ks] = *(const short8*)(Wtb + ((16 * w + c) * 1024 + mc * 128 + ks * 32 + q * 8));
        if (mc < 7) {
            #pragma unroll
            for (int mt = 0; mt < 8; mt++) {
                int m = (mc + 1) * 128 + mt * 16 + c;
                pb[mt] = (q < 2) ? *(const short8*)(zb + (m * 16 + q * 8)) : (short8)0;
                psc[mt] = z2h[m];
            }
        }
        __syncthreads();
        #pragma unroll
        for (int ks = 0; ks < 4; ks++) {
            #pragma unroll
            for (int nt = 0; nt < 4; nt++) {
                const short* tp = buf + (nt * 16 + c) * 132 + ks * 32 + q * 8;
                short4v lo = *(const short4v*)tp;
                short4v hi = *(const short4v*)(tp + 4);
                short8 bb = __builtin_shufflevector(lo, hi, 0, 1, 2, 3, 4, 5, 6, 7);
                acc[nt] = __builtin_amdgcn_mfma_f32_16x16x32_bf16(aw[ks], bb, acc[nt], 0, 0, 0);
            }
        }
    }

    // epilogue: D[row=q*4+r -> so=16w+..][col=c -> n]
    #pragma unroll
    for (int nt = 0; nt < 4; nt++) {
        #pragma unroll
        for (int r = 0; r < 4; r++) {
            out[(size_t)(16 * w + 4 * q + r) * N_PTS + n0 + nt * 16 + c] = acc[nt][r];
        }
    }
}

extern "C" void kernel_launch(void* const* d_in, const int* in_sizes, int n_in,
                              void* d_out, int out_size, void* d_ws, size_t ws_size,
                              hipStream_t stream) {
    const float* x  = (const float*)d_in[0];   // [65536][16]
    const float* z  = (const float*)d_in[1];   // [1024][16]
    const float* W  = (const float*)d_in[2];   // [8][8][1024] = [64][1024]
    const float* F  = (const float*)d_in[3];   // [8][16][64]
    const float* ph = (const float*)d_in[4];   // [8][64]
    const float* pw = (const float*)d_in[5];   // [8][8][64] = [64][64]
    float* out = (float*)d_out;                // [64][65536]

    char* ws = (char*)d_ws;
    short* zb  = (short*)(ws);            // 32768 B
    short* FbB = (short*)(ws + 32768);    // 16384 B
    short* BWd = (short*)(ws + 49152);    // 65536 B
    short* Wtb = (short*)(ws + 114688);   // 131072 B
    float* z2h = (float*)(ws + 245760);   // 4096 B
    float* phs = (float*)(ws + 249856);   // 2048 B

    prep_kernel<<<486, 256, 0, stream>>>(z, W, F, pw, ph, zb, FbB, BWd, Wtb, z2h, phs);
    fused_kernel<<<1024, 256, 0, stream>>>(x, zb, FbB, BWd, Wtb, z2h, phs, out);
}